// Round 11
// baseline (540.844 us; speedup 1.0000x reference)
//
#include <hip/hip_runtime.h>
#include <math.h>

#define NN 50000
#define EE 800000
#define INC 128
#define HIDC 64
#define OUTC 64
#define LLAYERS 8
#define TOT (EE + NN)
#define SCAN_B 200   // ceil(NN/256)

// Wave-internal LDS fence (vecs[w] is wave-private; no block barrier needed).
#define WAVE_LDS_FENCE() asm volatile("s_waitcnt lgkmcnt(0)" ::: "memory")

// Broadcast a float from a (compile-time-constant after unroll) lane.
__device__ __forceinline__ float rl(float v, int srclane) {
    return __uint_as_float(__builtin_amdgcn_readlane(__float_as_uint(v), srclane));
}

// ---------------------------------------------------------------------------
// Stage 0: detect whether edge_index was delivered as int64 or int32.
__global__ void detect_kernel(const long long* __restrict__ p, int* __restrict__ flag) {
    int stride = gridDim.x * blockDim.x;
    int bad = 0;
    for (int i = blockIdx.x * blockDim.x + threadIdx.x; i < EE; i += stride) {
        long long v = p[i];
        bad |= (v < 0 || v >= NN);
    }
    if (bad) atomicOr(flag, 1);   // flag=1 -> int32 layout
}

__device__ __forceinline__ int load_row(const void* ei, int is64, int e) {
    return is64 ? (int)((const long long*)ei)[e] : ((const int*)ei)[e];
}
__device__ __forceinline__ int load_col(const void* ei, int is64, int e) {
    return is64 ? (int)((const long long*)ei)[EE + e] : ((const int*)ei)[EE + e];
}

// Stage 1: in-degree of col (self-loops included)
__global__ void deg_kernel(const void* __restrict__ ei, const int* __restrict__ flag,
                           int* __restrict__ degi) {
    int i = blockIdx.x * blockDim.x + threadIdx.x;
    if (i >= TOT) return;
    int is64 = (*flag == 0);
    int c = (i < EE) ? load_col(ei, is64, i) : (i - EE);
    atomicAdd(&degi[c], 1);
}

__global__ void dinv_kernel(const int* __restrict__ degi, float* __restrict__ dinv) {
    int i = blockIdx.x * blockDim.x + threadIdx.x;
    if (i < NN) {
        int d = degi[i];
        dinv[i] = d > 0 ? 1.0f / sqrtf((float)d) : 0.0f;
    }
}

// ---------------------------------------------------------------------------
// Stage 2: 3-kernel device-wide exclusive scan
__global__ __launch_bounds__(256) void scan_part(const int* __restrict__ degi,
                                                 int* __restrict__ bsum) {
    __shared__ int s[256];
    int t = threadIdx.x;
    int i = blockIdx.x * 256 + t;
    s[t] = (i < NN) ? degi[i] : 0;
    __syncthreads();
    for (int off = 128; off > 0; off >>= 1) {
        if (t < off) s[t] += s[t + off];
        __syncthreads();
    }
    if (t == 0) bsum[blockIdx.x] = s[0];
}

__global__ __launch_bounds__(256) void scan_bsum(int* __restrict__ bsum) {
    __shared__ int s[256];
    int t = threadIdx.x;
    int v = (t < SCAN_B) ? bsum[t] : 0;
    s[t] = v;
    __syncthreads();
    for (int off = 1; off < 256; off <<= 1) {
        int add = (t >= off) ? s[t - off] : 0;
        __syncthreads();
        s[t] += add;
        __syncthreads();
    }
    if (t < SCAN_B) bsum[t] = s[t] - v;   // exclusive
}

__global__ __launch_bounds__(256) void scan_final(const int* __restrict__ degi,
                                                  const int* __restrict__ bsum,
                                                  int* __restrict__ offsets) {
    __shared__ int s[256];
    int t = threadIdx.x;
    int i = blockIdx.x * 256 + t;
    int v = (i < NN) ? degi[i] : 0;
    s[t] = v;
    __syncthreads();
    for (int off = 1; off < 256; off <<= 1) {
        int add = (t >= off) ? s[t - off] : 0;
        __syncthreads();
        s[t] += add;
        __syncthreads();
    }
    if (i < NN) {
        int off_i = bsum[blockIdx.x] + s[t] - v;   // exclusive prefix of degi[i]
        offsets[i] = off_i;
        if (i == NN - 1) offsets[NN] = off_i + v;
    }
}

// Stage 3: fill CSR adjacency (src, norm) sorted by destination
__global__ void fill_kernel(const void* __restrict__ ei, const int* __restrict__ flag,
                            const float* __restrict__ dinv, int* __restrict__ cursor,
                            int2* __restrict__ adj) {
    int i = blockIdx.x * blockDim.x + threadIdx.x;
    if (i >= TOT) return;
    int is64 = (*flag == 0);
    int r, c;
    if (i < EE) { r = load_row(ei, is64, i); c = load_col(ei, is64, i); }
    else        { r = i - EE; c = r; }
    int pos = atomicAdd(&cursor[c], 1);
    adj[pos] = make_int2(r, __float_as_int(dinv[r] * dinv[c]));
}

// ---------------------------------------------------------------------------
// Stage 4: h = relu(x @ w_in^T + b_in); also x0 = h.
// LDS-instruction-rate fix: each wave owns 4 nodes (16-lane group g loads node
// base+g's x row into registers). Dot loop shares ONE wT ds_read across 4 FMAs;
// the x operand broadcasts via v_readlane (VALU) -- zero LDS on that path.
// LDS instrs/node: 256 -> 32.
__global__ __launch_bounds__(512) void in_gemm(const float* __restrict__ x,
                                               const float* __restrict__ w_in,
                                               const float* __restrict__ b_in,
                                               float* __restrict__ h,
                                               float* __restrict__ x0) {
    __shared__ float wT[INC * 65];   // bank-spread: (k*65+j)%32 = (k+j)%32
    int tid = threadIdx.x;
    for (int i = tid; i < HIDC * INC; i += 512) {
        int j = i >> 7, k = i & 127;          // w_in[j][k], row-major [64][128]
        wT[k * 65 + j] = w_in[i];
    }
    __syncthreads();
    int w = tid >> 6, lane = tid & 63;
    int g = lane >> 4, c = lane & 15;
    float bj = b_in[lane];

    int base = blockIdx.x * 32 + w * 4;   // this wave's 4 nodes
    int n = base + g;                      // this group's node
    float4 xa = make_float4(0.f, 0.f, 0.f, 0.f);
    float4 xb = make_float4(0.f, 0.f, 0.f, 0.f);
    if (n < NN) {
        xa = *reinterpret_cast<const float4*>(x + (size_t)n * INC + (c << 2));
        xb = *reinterpret_cast<const float4*>(x + (size_t)n * INC + 64 + (c << 2));
    }
    float d0 = 0.f, d1 = 0.f, d2 = 0.f, d3 = 0.f;
    #pragma unroll
    for (int k = 0; k < INC; ++k) {
        float wv = wT[k * 65 + lane];
        int comp = k & 3;
        int sl   = (k & 63) >> 2;            // source lane within group
        float cr;
        if (k < 64) cr = (comp == 0) ? xa.x : (comp == 1) ? xa.y : (comp == 2) ? xa.z : xa.w;
        else        cr = (comp == 0) ? xb.x : (comp == 1) ? xb.y : (comp == 2) ? xb.z : xb.w;
        d0 = fmaf(rl(cr, sl),      wv, d0);
        d1 = fmaf(rl(cr, 16 + sl), wv, d1);
        d2 = fmaf(rl(cr, 32 + sl), wv, d2);
        d3 = fmaf(rl(cr, 48 + sl), wv, d3);
    }
    #pragma unroll
    for (int gg = 0; gg < 4; ++gg) {
        int nn_ = base + gg;
        if (nn_ < NN) {
            float dt = (gg == 0) ? d0 : (gg == 1) ? d1 : (gg == 2) ? d2 : d3;
            float v = fmaxf(dt + bj, 0.0f);
            h[((size_t)nn_ << 6) + lane]  = v;
            x0[((size_t)nn_ << 6) + lane] = v;
        }
    }
}

// ---------------------------------------------------------------------------
// Stage 5: GCNII layer. Wave owns 4 nodes; group g (16 lanes, c = channel
// quad) gathers node base+g COMPLETELY (no cross-group shuffle reduce -- the
// old 8 ds_bpermutes/node are gone). Dot: one WT ds_read shared across 4
// nodes' FMAs, agg broadcast via readlane. LDS instrs/node: ~130 -> ~17.
// Grid 3125 x 4 waves x 4 nodes = exactly 50000: no bounds checks.
__global__ __launch_bounds__(256) void layer_mid(
        const float* __restrict__ h_in, float* __restrict__ h_out,
        const float* __restrict__ x0,
        const int* __restrict__ offsets, const int2* __restrict__ adj,
        const float* __restrict__ W, float beta) {
    __shared__ float WT[HIDC * 65];
    __shared__ float vecs[4][4][HIDC];   // [wave][node][ch] -- residual readback
    int tid = threadIdx.x;
    for (int i = tid; i < HIDC * HIDC; i += 256) {
        int j = i >> 6, k = i & 63;
        WT[k * 65 + j] = W[i];
    }
    __syncthreads();
    int w = tid >> 6, lane = tid & 63;
    int g = lane >> 4, c = lane & 15;
    float omb = 1.0f - beta;

    int base = blockIdx.x * 16 + w * 4;
    int n = base + g;                      // exact cover: n < NN always
    int e0 = offsets[n], e1 = offsets[n + 1];
    float4 agg = make_float4(0.f, 0.f, 0.f, 0.f);
    #pragma unroll 2
    for (int e = e0; e < e1; ++e) {
        int2 a = adj[e];
        const float4 hv = *reinterpret_cast<const float4*>(h_in + ((a.x << 6) + (c << 2)));
        float nrm = __int_as_float(a.y);
        agg.x = fmaf(nrm, hv.x, agg.x);
        agg.y = fmaf(nrm, hv.y, agg.y);
        agg.z = fmaf(nrm, hv.z, agg.z);
        agg.w = fmaf(nrm, hv.w, agg.w);
    }
    {
        const float4 x0v = *reinterpret_cast<const float4*>(x0 + ((n << 6) + (c << 2)));
        agg.x = fmaf(0.9f, agg.x, 0.1f * x0v.x);
        agg.y = fmaf(0.9f, agg.y, 0.1f * x0v.y);
        agg.z = fmaf(0.9f, agg.z, 0.1f * x0v.z);
        agg.w = fmaf(0.9f, agg.w, 0.1f * x0v.w);
        *reinterpret_cast<float4*>(&vecs[w][g][c << 2]) = agg;
    }
    WAVE_LDS_FENCE();

    float d0 = 0.f, d1 = 0.f, d2 = 0.f, d3 = 0.f;
    #pragma unroll
    for (int k = 0; k < HIDC; ++k) {
        float wv = WT[k * 65 + lane];
        int comp = k & 3;
        int sl   = k >> 2;
        float cr = (comp == 0) ? agg.x : (comp == 1) ? agg.y : (comp == 2) ? agg.z : agg.w;
        d0 = fmaf(rl(cr, sl),      wv, d0);
        d1 = fmaf(rl(cr, 16 + sl), wv, d1);
        d2 = fmaf(rl(cr, 32 + sl), wv, d2);
        d3 = fmaf(rl(cr, 48 + sl), wv, d3);
    }
    #pragma unroll
    for (int gg = 0; gg < 4; ++gg) {
        float vagg = vecs[w][gg][lane];
        float dt = (gg == 0) ? d0 : (gg == 1) ? d1 : (gg == 2) ? d2 : d3;
        float hn = fmaxf(fmaf(beta, dt, omb * vagg), 0.0f);
        h_out[((base + gg) << 6) + lane] = hn;
    }
}

// ---------------------------------------------------------------------------
// Stage 6: out = h @ w_out^T + b_out, same 4-node readlane structure.
__global__ __launch_bounds__(256) void out_gemm(const float* __restrict__ h,
                                                const float* __restrict__ w_out,
                                                const float* __restrict__ b_out,
                                                float* __restrict__ out) {
    __shared__ float WoT[HIDC * 65];
    int tid = threadIdx.x;
    for (int i = tid; i < HIDC * HIDC; i += 256) {
        int j = i >> 6, k = i & 63;
        WoT[k * 65 + j] = w_out[i];
    }
    __syncthreads();
    int w = tid >> 6, lane = tid & 63;
    int g = lane >> 4, c = lane & 15;
    float bj = b_out[lane];

    int base = blockIdx.x * 16 + w * 4;
    int n = base + g;                      // exact cover
    float4 hvq = *reinterpret_cast<const float4*>(h + ((n << 6) + (c << 2)));

    float d0 = 0.f, d1 = 0.f, d2 = 0.f, d3 = 0.f;
    #pragma unroll
    for (int k = 0; k < HIDC; ++k) {
        float wv = WoT[k * 65 + lane];
        int comp = k & 3;
        int sl   = k >> 2;
        float cr = (comp == 0) ? hvq.x : (comp == 1) ? hvq.y : (comp == 2) ? hvq.z : hvq.w;
        d0 = fmaf(rl(cr, sl),      wv, d0);
        d1 = fmaf(rl(cr, 16 + sl), wv, d1);
        d2 = fmaf(rl(cr, 32 + sl), wv, d2);
        d3 = fmaf(rl(cr, 48 + sl), wv, d3);
    }
    #pragma unroll
    for (int gg = 0; gg < 4; ++gg) {
        float dt = (gg == 0) ? d0 : (gg == 1) ? d1 : (gg == 2) ? d2 : d3;
        out[((base + gg) << 6) + lane] = dt + bj;
    }
}

extern "C" void kernel_launch(void* const* d_in, const int* in_sizes, int n_in,
                              void* d_out, int out_size, void* d_ws, size_t ws_size,
                              hipStream_t stream) {
    const float* x      = (const float*)d_in[0];
    const void*  ei     = d_in[1];
    const float* w_in   = (const float*)d_in[2];
    const float* b_in   = (const float*)d_in[3];
    const float* conv_w = (const float*)d_in[4];
    const float* w_out  = (const float*)d_in[5];
    const float* b_out  = (const float*)d_in[6];
    float* out = (float*)d_out;

    char* ws = (char*)d_ws;
    size_t off = 0;
    auto alloc = [&](size_t bytes) -> void* {
        void* p = ws + off;
        off += (bytes + 255) & ~(size_t)255;
        return p;
    };
    int*   flag    = (int*)alloc(4);
    int*   degi    = (int*)alloc((size_t)NN * 4);
    float* dinv    = (float*)alloc((size_t)NN * 4);
    int*   offsets = (int*)alloc((size_t)(NN + 1) * 4);
    int*   cursor  = (int*)alloc((size_t)NN * 4);
    int*   bsum    = (int*)alloc((size_t)SCAN_B * 4);
    int2*  adj     = (int2*)alloc((size_t)TOT * 8);
    float* hA      = (float*)alloc((size_t)NN * HIDC * 4);
    float* hB      = (float*)alloc((size_t)NN * HIDC * 4);
    float* x0      = (float*)alloc((size_t)NN * HIDC * 4);

    hipMemsetAsync(flag, 0, 4, stream);
    hipMemsetAsync(degi, 0, (size_t)NN * 4, stream);
    detect_kernel<<<256, 256, 0, stream>>>((const long long*)ei, flag);
    deg_kernel<<<(TOT + 255) / 256, 256, 0, stream>>>(ei, flag, degi);
    dinv_kernel<<<(NN + 255) / 256, 256, 0, stream>>>(degi, dinv);
    scan_part<<<SCAN_B, 256, 0, stream>>>(degi, bsum);
    scan_bsum<<<1, 256, 0, stream>>>(bsum);
    scan_final<<<SCAN_B, 256, 0, stream>>>(degi, bsum, offsets);
    hipMemcpyAsync(cursor, offsets, (size_t)NN * 4, hipMemcpyDeviceToDevice, stream);
    fill_kernel<<<(TOT + 255) / 256, 256, 0, stream>>>(ei, flag, dinv, cursor, adj);
    in_gemm<<<(NN + 31) / 32, 512, 0, stream>>>(x, w_in, b_in, hA, x0);

    float* cur = hA;
    float* nxt = hB;
    for (int l = 0; l < LLAYERS; ++l) {
        float beta = logf(0.5f / (float)(l + 1) + 1.0f);
        const float* Wl = conv_w + (size_t)l * HIDC * HIDC;
        layer_mid<<<NN / 16, 256, 0, stream>>>(cur, nxt, x0, offsets, adj, Wl, beta);
        float* t = cur; cur = nxt; nxt = t;
    }
    out_gemm<<<NN / 16, 256, 0, stream>>>(cur, w_out, b_out, out);
}

// Round 12
// 442.301 us; speedup vs baseline: 1.2228x; 1.2228x over previous
//
#include <hip/hip_runtime.h>
#include <math.h>

#define NN 50000
#define EE 800000
#define INC 128
#define HIDC 64
#define OUTC 64
#define LLAYERS 8
#define TOT (EE + NN)
#define SCAN_B 200   // ceil(NN/256)

// Wave-internal LDS fence (vecs[w]/xs[w] wave-private; no block barrier).
#define WAVE_LDS_FENCE() asm volatile("s_waitcnt lgkmcnt(0)" ::: "memory")

// bf16 <-> f32 (RTN-even pack; values are finite)
__device__ __forceinline__ float bf2f(unsigned short u) {
    return __uint_as_float(((unsigned int)u) << 16);
}
__device__ __forceinline__ unsigned short f2bf(float f) {
    unsigned int u = __float_as_uint(f);
    u += 0x7FFFu + ((u >> 16) & 1u);
    return (unsigned short)(u >> 16);
}

// ---------------------------------------------------------------------------
// Stage 0: detect whether edge_index was delivered as int64 or int32.
__global__ void detect_kernel(const long long* __restrict__ p, int* __restrict__ flag) {
    int stride = gridDim.x * blockDim.x;
    int bad = 0;
    for (int i = blockIdx.x * blockDim.x + threadIdx.x; i < EE; i += stride) {
        long long v = p[i];
        bad |= (v < 0 || v >= NN);
    }
    if (bad) atomicOr(flag, 1);   // flag=1 -> int32 layout
}

__device__ __forceinline__ int load_row(const void* ei, int is64, int e) {
    return is64 ? (int)((const long long*)ei)[e] : ((const int*)ei)[e];
}
__device__ __forceinline__ int load_col(const void* ei, int is64, int e) {
    return is64 ? (int)((const long long*)ei)[EE + e] : ((const int*)ei)[EE + e];
}

// Stage 1: in-degree of col (self-loops included)
__global__ void deg_kernel(const void* __restrict__ ei, const int* __restrict__ flag,
                           int* __restrict__ degi) {
    int i = blockIdx.x * blockDim.x + threadIdx.x;
    if (i >= TOT) return;
    int is64 = (*flag == 0);
    int c = (i < EE) ? load_col(ei, is64, i) : (i - EE);
    atomicAdd(&degi[c], 1);
}

__global__ void dinv_kernel(const int* __restrict__ degi, float* __restrict__ dinv) {
    int i = blockIdx.x * blockDim.x + threadIdx.x;
    if (i < NN) {
        int d = degi[i];
        dinv[i] = d > 0 ? 1.0f / sqrtf((float)d) : 0.0f;
    }
}

// ---------------------------------------------------------------------------
// Stage 2: 3-kernel device-wide exclusive scan
__global__ __launch_bounds__(256) void scan_part(const int* __restrict__ degi,
                                                 int* __restrict__ bsum) {
    __shared__ int s[256];
    int t = threadIdx.x;
    int i = blockIdx.x * 256 + t;
    s[t] = (i < NN) ? degi[i] : 0;
    __syncthreads();
    for (int off = 128; off > 0; off >>= 1) {
        if (t < off) s[t] += s[t + off];
        __syncthreads();
    }
    if (t == 0) bsum[blockIdx.x] = s[0];
}

__global__ __launch_bounds__(256) void scan_bsum(int* __restrict__ bsum) {
    __shared__ int s[256];
    int t = threadIdx.x;
    int v = (t < SCAN_B) ? bsum[t] : 0;
    s[t] = v;
    __syncthreads();
    for (int off = 1; off < 256; off <<= 1) {
        int add = (t >= off) ? s[t - off] : 0;
        __syncthreads();
        s[t] += add;
        __syncthreads();
    }
    if (t < SCAN_B) bsum[t] = s[t] - v;   // exclusive
}

__global__ __launch_bounds__(256) void scan_final(const int* __restrict__ degi,
                                                  const int* __restrict__ bsum,
                                                  int* __restrict__ offsets) {
    __shared__ int s[256];
    int t = threadIdx.x;
    int i = blockIdx.x * 256 + t;
    int v = (i < NN) ? degi[i] : 0;
    s[t] = v;
    __syncthreads();
    for (int off = 1; off < 256; off <<= 1) {
        int add = (t >= off) ? s[t - off] : 0;
        __syncthreads();
        s[t] += add;
        __syncthreads();
    }
    if (i < NN) {
        int off_i = bsum[blockIdx.x] + s[t] - v;   // exclusive prefix of degi[i]
        offsets[i] = off_i;
        if (i == NN - 1) offsets[NN] = off_i + v;
    }
}

// Stage 3: fill CSR adjacency (src, norm) sorted by destination
__global__ void fill_kernel(const void* __restrict__ ei, const int* __restrict__ flag,
                            const float* __restrict__ dinv, int* __restrict__ cursor,
                            int2* __restrict__ adj) {
    int i = blockIdx.x * blockDim.x + threadIdx.x;
    if (i >= TOT) return;
    int is64 = (*flag == 0);
    int r, c;
    if (i < EE) { r = load_row(ei, is64, i); c = load_col(ei, is64, i); }
    else        { r = i - EE; c = r; }
    int pos = atomicAdd(&cursor[c], 1);
    adj[pos] = make_int2(r, __float_as_int(dinv[r] * dinv[c]));
}

// Stage 4: h(bf16) = relu(x @ w_in^T + b_in); x0(fp32) = same.
// R10's proven 512-thread / 65-pad structure (conflict-free, 48us).
__global__ __launch_bounds__(512) void in_gemm(const float* __restrict__ x,
                                               const float* __restrict__ w_in,
                                               const float* __restrict__ b_in,
                                               unsigned short* __restrict__ h,
                                               float* __restrict__ x0) {
    __shared__ float wT[INC * 65];
    __shared__ float xs[8][INC];
    int tid = threadIdx.x;
    for (int i = tid; i < HIDC * INC; i += 512) {
        int j = i >> 7, k = i & 127;          // w_in[j][k], row-major [64][128]
        wT[k * 65 + j] = w_in[i];
    }
    __syncthreads();
    int w = tid >> 6, lane = tid & 63;
    float bj = b_in[lane];
    for (int n0 = blockIdx.x * 8; n0 < NN; n0 += gridDim.x * 8) {
        int n = n0 + w;
        if (n < NN) {
            xs[w][lane]      = x[(size_t)n * INC + lane];
            xs[w][lane + 64] = x[(size_t)n * INC + 64 + lane];
            WAVE_LDS_FENCE();
            float acc = bj;
            #pragma unroll 8
            for (int k = 0; k < INC; ++k)
                acc = fmaf(xs[w][k], wT[k * 65 + lane], acc);
            float v = fmaxf(acc, 0.0f);
            h[((size_t)n << 6) + lane]  = f2bf(v);
            x0[((size_t)n << 6) + lane] = v;
        }
    }
}

// ---------------------------------------------------------------------------
// Gather core (bf16 h rows): wave handles node n. lane = g*16 + c. Group g
// walks edges e0+g, e0+g+4, ... Each lane loads ushort4 (8B = 4 bf16) -> wave
// fetches 4 distinct 128B rows per instruction. fp32 accumulate.
__device__ __forceinline__ float4 gather_node(const unsigned short* __restrict__ h_in,
                                              const int2* __restrict__ adj,
                                              int e0, int e1, int g, int c) {
    float4 acc = make_float4(0.f, 0.f, 0.f, 0.f);
    #pragma unroll 2
    for (int e = e0 + g; e < e1; e += 4) {
        int2 a = adj[e];
        ushort4 hv = *reinterpret_cast<const ushort4*>(h_in + ((a.x << 6) + (c << 2)));
        float nrm = __int_as_float(a.y);
        acc.x = fmaf(nrm, bf2f(hv.x), acc.x);
        acc.y = fmaf(nrm, bf2f(hv.y), acc.y);
        acc.z = fmaf(nrm, bf2f(hv.z), acc.z);
        acc.w = fmaf(nrm, bf2f(hv.w), acc.w);
    }
    // reduce across the 4 groups (lanes differing in bits 4..5)
    acc.x += __shfl_xor(acc.x, 16); acc.y += __shfl_xor(acc.y, 16);
    acc.z += __shfl_xor(acc.z, 16); acc.w += __shfl_xor(acc.w, 16);
    acc.x += __shfl_xor(acc.x, 32); acc.y += __shfl_xor(acc.y, 32);
    acc.z += __shfl_xor(acc.z, 32); acc.w += __shfl_xor(acc.w, 32);
    return acc;
}

// Stage 5: GCNII layer (all 8). R8/R10 proven structure; only h dtype changed.
__global__ __launch_bounds__(256, 8) void layer_mid(
        const unsigned short* __restrict__ h_in, unsigned short* __restrict__ h_out,
        const float* __restrict__ x0,
        const int* __restrict__ offsets, const int2* __restrict__ adj,
        const float* __restrict__ W, float beta) {
    __shared__ float WT[HIDC * 65];
    __shared__ float vecs[4][HIDC];
    int tid = threadIdx.x;
    for (int i = tid; i < HIDC * HIDC; i += 256) {
        int j = i >> 6, k = i & 63;
        WT[k * 65 + j] = W[i];
    }
    __syncthreads();
    int w = tid >> 6, lane = tid & 63;
    int g = lane >> 4, c = lane & 15;
    float omb = 1.0f - beta;

    for (int n0 = blockIdx.x * 4; n0 < NN; n0 += gridDim.x * 4) {
        int n = n0 + w;
        if (n < NN) {                          // uniform per wave
            int e0 = offsets[n], e1 = offsets[n + 1];
            float4 acc = gather_node(h_in, adj, e0, e1, g, c);
            if (g == 0) {
                const float4 x0v = *reinterpret_cast<const float4*>(x0 + ((n << 6) + (c << 2)));
                float4 aggv;
                aggv.x = fmaf(0.9f, acc.x, 0.1f * x0v.x);
                aggv.y = fmaf(0.9f, acc.y, 0.1f * x0v.y);
                aggv.z = fmaf(0.9f, acc.z, 0.1f * x0v.z);
                aggv.w = fmaf(0.9f, acc.w, 0.1f * x0v.w);
                *reinterpret_cast<float4*>(&vecs[w][c << 2]) = aggv;
            }
            WAVE_LDS_FENCE();
            float vagg = vecs[w][lane];
            float dot = 0.0f;
            #pragma unroll 8
            for (int k = 0; k < HIDC; ++k)
                dot = fmaf(vecs[w][k], WT[k * 65 + lane], dot);
            float hn = fmaxf(fmaf(beta, dot, omb * vagg), 0.0f);
            h_out[(n << 6) + lane] = f2bf(hn);
        }
    }
}

// Stage 6: out = h @ w_out^T + b_out (h is bf16; dot fp32).
__global__ __launch_bounds__(256, 8) void out_gemm(const unsigned short* __restrict__ h,
                                                   const float* __restrict__ w_out,
                                                   const float* __restrict__ b_out,
                                                   float* __restrict__ out) {
    __shared__ float WoT[HIDC * 65];
    __shared__ float vecs[4][HIDC];
    int tid = threadIdx.x;
    for (int i = tid; i < HIDC * HIDC; i += 256) {
        int j = i >> 6, k = i & 63;
        WoT[k * 65 + j] = w_out[i];
    }
    __syncthreads();
    int w = tid >> 6, lane = tid & 63;
    float bj = b_out[lane];
    for (int n0 = blockIdx.x * 4; n0 < NN; n0 += gridDim.x * 4) {
        int n = n0 + w;
        if (n < NN) {
            vecs[w][lane] = bf2f(h[(n << 6) + lane]);
            WAVE_LDS_FENCE();
            float acc = bj;
            #pragma unroll 8
            for (int k = 0; k < HIDC; ++k)
                acc = fmaf(vecs[w][k], WoT[k * 65 + lane], acc);
            out[(n << 6) + lane] = acc;
        }
    }
}

extern "C" void kernel_launch(void* const* d_in, const int* in_sizes, int n_in,
                              void* d_out, int out_size, void* d_ws, size_t ws_size,
                              hipStream_t stream) {
    const float* x      = (const float*)d_in[0];
    const void*  ei     = d_in[1];
    const float* w_in   = (const float*)d_in[2];
    const float* b_in   = (const float*)d_in[3];
    const float* conv_w = (const float*)d_in[4];
    const float* w_out  = (const float*)d_in[5];
    const float* b_out  = (const float*)d_in[6];
    float* out = (float*)d_out;

    char* ws = (char*)d_ws;
    size_t off = 0;
    auto alloc = [&](size_t bytes) -> void* {
        void* p = ws + off;
        off += (bytes + 255) & ~(size_t)255;
        return p;
    };
    int*   flag    = (int*)alloc(4);
    int*   degi    = (int*)alloc((size_t)NN * 4);
    float* dinv    = (float*)alloc((size_t)NN * 4);
    int*   offsets = (int*)alloc((size_t)(NN + 1) * 4);
    int*   cursor  = (int*)alloc((size_t)NN * 4);
    int*   bsum    = (int*)alloc((size_t)SCAN_B * 4);
    int2*  adj     = (int2*)alloc((size_t)TOT * 8);
    unsigned short* hA = (unsigned short*)alloc((size_t)NN * HIDC * 2);
    unsigned short* hB = (unsigned short*)alloc((size_t)NN * HIDC * 2);
    float* x0      = (float*)alloc((size_t)NN * HIDC * 4);

    hipMemsetAsync(flag, 0, 4, stream);
    hipMemsetAsync(degi, 0, (size_t)NN * 4, stream);
    detect_kernel<<<256, 256, 0, stream>>>((const long long*)ei, flag);
    deg_kernel<<<(TOT + 255) / 256, 256, 0, stream>>>(ei, flag, degi);
    dinv_kernel<<<(NN + 255) / 256, 256, 0, stream>>>(degi, dinv);
    scan_part<<<SCAN_B, 256, 0, stream>>>(degi, bsum);
    scan_bsum<<<1, 256, 0, stream>>>(bsum);
    scan_final<<<SCAN_B, 256, 0, stream>>>(degi, bsum, offsets);
    hipMemcpyAsync(cursor, offsets, (size_t)NN * 4, hipMemcpyDeviceToDevice, stream);
    fill_kernel<<<(TOT + 255) / 256, 256, 0, stream>>>(ei, flag, dinv, cursor, adj);
    in_gemm<<<1024, 512, 0, stream>>>(x, w_in, b_in, hA, x0);

    unsigned short* cur = hA;
    unsigned short* nxt = hB;
    for (int l = 0; l < LLAYERS; ++l) {
        float beta = logf(0.5f / (float)(l + 1) + 1.0f);
        const float* Wl = conv_w + (size_t)l * HIDC * HIDC;
        layer_mid<<<2048, 256, 0, stream>>>(cur, nxt, x0, offsets, adj, Wl, beta);
        unsigned short* t = cur; cur = nxt; nxt = t;
    }
    out_gemm<<<1024, 256, 0, stream>>>(cur, w_out, b_out, out);
}

// Round 13
// 423.906 us; speedup vs baseline: 1.2759x; 1.0434x over previous
//
#include <hip/hip_runtime.h>
#include <math.h>

#define NN 50000
#define EE 800000
#define INC 128
#define HIDC 64
#define OUTC 64
#define LLAYERS 8
#define TOT (EE + NN)
#define SCAN_B 200   // ceil(NN/256)

// Wave-internal LDS fence (vecs[w]/xs[w] wave-private; no block barrier).
#define WAVE_LDS_FENCE() asm volatile("s_waitcnt lgkmcnt(0)" ::: "memory")

// bf16 <-> f32 (RTN-even pack; values are finite)
__device__ __forceinline__ float bf2f(unsigned short u) {
    return __uint_as_float(((unsigned int)u) << 16);
}
__device__ __forceinline__ unsigned short f2bf(float f) {
    unsigned int u = __float_as_uint(f);
    u += 0x7FFFu + ((u >> 16) & 1u);
    return (unsigned short)(u >> 16);
}

// ---------------------------------------------------------------------------
// Stage 0: detect whether edge_index was delivered as int64 or int32.
__global__ void detect_kernel(const long long* __restrict__ p, int* __restrict__ flag) {
    int stride = gridDim.x * blockDim.x;
    int bad = 0;
    for (int i = blockIdx.x * blockDim.x + threadIdx.x; i < EE; i += stride) {
        long long v = p[i];
        bad |= (v < 0 || v >= NN);
    }
    if (bad) atomicOr(flag, 1);   // flag=1 -> int32 layout
}

__device__ __forceinline__ int load_row(const void* ei, int is64, int e) {
    return is64 ? (int)((const long long*)ei)[e] : ((const int*)ei)[e];
}
__device__ __forceinline__ int load_col(const void* ei, int is64, int e) {
    return is64 ? (int)((const long long*)ei)[EE + e] : ((const int*)ei)[EE + e];
}

// Stage 1: in-degree of col (self-loops included)
__global__ void deg_kernel(const void* __restrict__ ei, const int* __restrict__ flag,
                           int* __restrict__ degi) {
    int i = blockIdx.x * blockDim.x + threadIdx.x;
    if (i >= TOT) return;
    int is64 = (*flag == 0);
    int c = (i < EE) ? load_col(ei, is64, i) : (i - EE);
    atomicAdd(&degi[c], 1);
}

__global__ void dinv_kernel(const int* __restrict__ degi, float* __restrict__ dinv) {
    int i = blockIdx.x * blockDim.x + threadIdx.x;
    if (i < NN) {
        int d = degi[i];
        dinv[i] = d > 0 ? 1.0f / sqrtf((float)d) : 0.0f;
    }
}

// ---------------------------------------------------------------------------
// Stage 2: 3-kernel device-wide exclusive scan
__global__ __launch_bounds__(256) void scan_part(const int* __restrict__ degi,
                                                 int* __restrict__ bsum) {
    __shared__ int s[256];
    int t = threadIdx.x;
    int i = blockIdx.x * 256 + t;
    s[t] = (i < NN) ? degi[i] : 0;
    __syncthreads();
    for (int off = 128; off > 0; off >>= 1) {
        if (t < off) s[t] += s[t + off];
        __syncthreads();
    }
    if (t == 0) bsum[blockIdx.x] = s[0];
}

__global__ __launch_bounds__(256) void scan_bsum(int* __restrict__ bsum) {
    __shared__ int s[256];
    int t = threadIdx.x;
    int v = (t < SCAN_B) ? bsum[t] : 0;
    s[t] = v;
    __syncthreads();
    for (int off = 1; off < 256; off <<= 1) {
        int add = (t >= off) ? s[t - off] : 0;
        __syncthreads();
        s[t] += add;
        __syncthreads();
    }
    if (t < SCAN_B) bsum[t] = s[t] - v;   // exclusive
}

__global__ __launch_bounds__(256) void scan_final(const int* __restrict__ degi,
                                                  const int* __restrict__ bsum,
                                                  int* __restrict__ offsets) {
    __shared__ int s[256];
    int t = threadIdx.x;
    int i = blockIdx.x * 256 + t;
    int v = (i < NN) ? degi[i] : 0;
    s[t] = v;
    __syncthreads();
    for (int off = 1; off < 256; off <<= 1) {
        int add = (t >= off) ? s[t - off] : 0;
        __syncthreads();
        s[t] += add;
        __syncthreads();
    }
    if (i < NN) {
        int off_i = bsum[blockIdx.x] + s[t] - v;   // exclusive prefix of degi[i]
        offsets[i] = off_i;
        if (i == NN - 1) offsets[NN] = off_i + v;
    }
}

// Stage 3: fill CSR adjacency (src, norm) sorted by destination
__global__ void fill_kernel(const void* __restrict__ ei, const int* __restrict__ flag,
                            const float* __restrict__ dinv, int* __restrict__ cursor,
                            int2* __restrict__ adj) {
    int i = blockIdx.x * blockDim.x + threadIdx.x;
    if (i >= TOT) return;
    int is64 = (*flag == 0);
    int r, c;
    if (i < EE) { r = load_row(ei, is64, i); c = load_col(ei, is64, i); }
    else        { r = i - EE; c = r; }
    int pos = atomicAdd(&cursor[c], 1);
    adj[pos] = make_int2(r, __float_as_int(dinv[r] * dinv[c]));
}

// ---------------------------------------------------------------------------
// Stage 4: h(bf16) = relu(x @ w_in^T + b_in); x0(fp32) = same.
// Dot vectorized: W stored ROW-major per output channel (lane reads its own
// row as 32 x float4 ds_read_b128), 16B-slot XOR-swizzled (slot ^ (lane&7))
// so the 8 rows of each lane-octet hit 8 distinct bank clusters. x operand:
// uniform float4 broadcast. LDS instrs/node: 256 -> 64.
__global__ __launch_bounds__(512) void in_gemm(const float* __restrict__ x,
                                               const float* __restrict__ w_in,
                                               const float* __restrict__ b_in,
                                               unsigned short* __restrict__ h,
                                               float* __restrict__ x0) {
    __shared__ float wR[HIDC * INC];   // row j at j*128, slot-swizzled
    __shared__ float xs[8][INC];
    int tid = threadIdx.x;
    for (int i = tid; i < HIDC * INC; i += 512) {
        int j = i >> 7, k = i & 127;          // w_in[j][k], row-major [64][128]
        int s = k >> 2;
        int sp = s ^ (j & 7);                 // storage slot
        wR[(j << 7) + (sp << 2) + (k & 3)] = w_in[i];
    }
    __syncthreads();
    int w = tid >> 6, lane = tid & 63;
    int jx = lane & 7;
    float bj = b_in[lane];
    for (int n0 = blockIdx.x * 8; n0 < NN; n0 += gridDim.x * 8) {
        int n = n0 + w;
        if (n < NN) {
            xs[w][lane]      = x[(size_t)n * INC + lane];
            xs[w][lane + 64] = x[(size_t)n * INC + 64 + lane];
            WAVE_LDS_FENCE();
            float acc = bj;
            #pragma unroll
            for (int s = 0; s < 32; ++s) {
                float4 wv = *reinterpret_cast<const float4*>(&wR[(lane << 7) + ((s ^ jx) << 2)]);
                float4 xv = *reinterpret_cast<const float4*>(&xs[w][s << 2]);
                acc = fmaf(wv.x, xv.x, acc);
                acc = fmaf(wv.y, xv.y, acc);
                acc = fmaf(wv.z, xv.z, acc);
                acc = fmaf(wv.w, xv.w, acc);
            }
            float v = fmaxf(acc, 0.0f);
            h[((size_t)n << 6) + lane]  = f2bf(v);
            x0[((size_t)n << 6) + lane] = v;
        }
    }
}

// ---------------------------------------------------------------------------
// Gather core (bf16 h rows): wave handles node n. lane = g*16 + c. Group g
// walks edges e0+g, e0+g+4, ... Each lane loads ushort4 (8B = 4 bf16) -> wave
// fetches 4 distinct 128B rows per instruction. fp32 accumulate.
__device__ __forceinline__ float4 gather_node(const unsigned short* __restrict__ h_in,
                                              const int2* __restrict__ adj,
                                              int e0, int e1, int g, int c) {
    float4 acc = make_float4(0.f, 0.f, 0.f, 0.f);
    #pragma unroll 2
    for (int e = e0 + g; e < e1; e += 4) {
        int2 a = adj[e];
        ushort4 hv = *reinterpret_cast<const ushort4*>(h_in + ((a.x << 6) + (c << 2)));
        float nrm = __int_as_float(a.y);
        acc.x = fmaf(nrm, bf2f(hv.x), acc.x);
        acc.y = fmaf(nrm, bf2f(hv.y), acc.y);
        acc.z = fmaf(nrm, bf2f(hv.z), acc.z);
        acc.w = fmaf(nrm, bf2f(hv.w), acc.w);
    }
    // reduce across the 4 groups (lanes differing in bits 4..5)
    acc.x += __shfl_xor(acc.x, 16); acc.y += __shfl_xor(acc.y, 16);
    acc.z += __shfl_xor(acc.z, 16); acc.w += __shfl_xor(acc.w, 16);
    acc.x += __shfl_xor(acc.x, 32); acc.y += __shfl_xor(acc.y, 32);
    acc.z += __shfl_xor(acc.z, 32); acc.w += __shfl_xor(acc.w, 32);
    return acc;
}

// Stage 5: GCNII layer (all 8). Gather unchanged; dot vectorized to b128
// with the same row-major + slot-XOR-swizzle W layout (16 x float4 per row)
// and uniform float4 broadcast for vecs. LDS instrs/node: ~137 -> ~41.
__global__ __launch_bounds__(256, 8) void layer_mid(
        const unsigned short* __restrict__ h_in, unsigned short* __restrict__ h_out,
        const float* __restrict__ x0,
        const int* __restrict__ offsets, const int2* __restrict__ adj,
        const float* __restrict__ W, float beta) {
    __shared__ float WR[HIDC * HIDC];   // row j at j*64, slot-swizzled
    __shared__ float vecs[4][HIDC];
    int tid = threadIdx.x;
    for (int i = tid; i < HIDC * HIDC; i += 256) {
        int j = i >> 6, k = i & 63;           // W[j][k]
        int s = k >> 2;
        int sp = s ^ (j & 7);
        WR[(j << 6) + (sp << 2) + (k & 3)] = W[i];
    }
    __syncthreads();
    int w = tid >> 6, lane = tid & 63;
    int g = lane >> 4, c = lane & 15;
    int jx = lane & 7;
    float omb = 1.0f - beta;

    for (int n0 = blockIdx.x * 4; n0 < NN; n0 += gridDim.x * 4) {
        int n = n0 + w;
        if (n < NN) {                          // uniform per wave
            int e0 = offsets[n], e1 = offsets[n + 1];
            float4 acc = gather_node(h_in, adj, e0, e1, g, c);
            if (g == 0) {
                const float4 x0v = *reinterpret_cast<const float4*>(x0 + ((n << 6) + (c << 2)));
                float4 aggv;
                aggv.x = fmaf(0.9f, acc.x, 0.1f * x0v.x);
                aggv.y = fmaf(0.9f, acc.y, 0.1f * x0v.y);
                aggv.z = fmaf(0.9f, acc.z, 0.1f * x0v.z);
                aggv.w = fmaf(0.9f, acc.w, 0.1f * x0v.w);
                *reinterpret_cast<float4*>(&vecs[w][c << 2]) = aggv;
            }
            WAVE_LDS_FENCE();
            float vagg = vecs[w][lane];
            float dot = 0.0f;
            #pragma unroll
            for (int s = 0; s < 16; ++s) {
                float4 wv = *reinterpret_cast<const float4*>(&WR[(lane << 6) + ((s ^ jx) << 2)]);
                float4 vv = *reinterpret_cast<const float4*>(&vecs[w][s << 2]);
                dot = fmaf(wv.x, vv.x, dot);
                dot = fmaf(wv.y, vv.y, dot);
                dot = fmaf(wv.z, vv.z, dot);
                dot = fmaf(wv.w, vv.w, dot);
            }
            float hn = fmaxf(fmaf(beta, dot, omb * vagg), 0.0f);
            h_out[(n << 6) + lane] = f2bf(hn);
        }
    }
}

// Stage 6: out = h @ w_out^T + b_out (h bf16; same vectorized dot).
__global__ __launch_bounds__(256, 8) void out_gemm(const unsigned short* __restrict__ h,
                                                   const float* __restrict__ w_out,
                                                   const float* __restrict__ b_out,
                                                   float* __restrict__ out) {
    __shared__ float WR[HIDC * HIDC];
    __shared__ float vecs[4][HIDC];
    int tid = threadIdx.x;
    for (int i = tid; i < HIDC * HIDC; i += 256) {
        int j = i >> 6, k = i & 63;
        int s = k >> 2;
        int sp = s ^ (j & 7);
        WR[(j << 6) + (sp << 2) + (k & 3)] = w_out[i];
    }
    __syncthreads();
    int w = tid >> 6, lane = tid & 63;
    int jx = lane & 7;
    float bj = b_out[lane];
    for (int n0 = blockIdx.x * 4; n0 < NN; n0 += gridDim.x * 4) {
        int n = n0 + w;
        if (n < NN) {
            vecs[w][lane] = bf2f(h[(n << 6) + lane]);
            WAVE_LDS_FENCE();
            float acc = bj;
            #pragma unroll
            for (int s = 0; s < 16; ++s) {
                float4 wv = *reinterpret_cast<const float4*>(&WR[(lane << 6) + ((s ^ jx) << 2)]);
                float4 vv = *reinterpret_cast<const float4*>(&vecs[w][s << 2]);
                acc = fmaf(wv.x, vv.x, acc);
                acc = fmaf(wv.y, vv.y, acc);
                acc = fmaf(wv.z, vv.z, acc);
                acc = fmaf(wv.w, vv.w, acc);
            }
            out[(n << 6) + lane] = acc;
        }
    }
}

extern "C" void kernel_launch(void* const* d_in, const int* in_sizes, int n_in,
                              void* d_out, int out_size, void* d_ws, size_t ws_size,
                              hipStream_t stream) {
    const float* x      = (const float*)d_in[0];
    const void*  ei     = d_in[1];
    const float* w_in   = (const float*)d_in[2];
    const float* b_in   = (const float*)d_in[3];
    const float* conv_w = (const float*)d_in[4];
    const float* w_out  = (const float*)d_in[5];
    const float* b_out  = (const float*)d_in[6];
    float* out = (float*)d_out;

    char* ws = (char*)d_ws;
    size_t off = 0;
    auto alloc = [&](size_t bytes) -> void* {
        void* p = ws + off;
        off += (bytes + 255) & ~(size_t)255;
        return p;
    };
    int*   flag    = (int*)alloc(4);
    int*   degi    = (int*)alloc((size_t)NN * 4);
    float* dinv    = (float*)alloc((size_t)NN * 4);
    int*   offsets = (int*)alloc((size_t)(NN + 1) * 4);
    int*   cursor  = (int*)alloc((size_t)NN * 4);
    int*   bsum    = (int*)alloc((size_t)SCAN_B * 4);
    int2*  adj     = (int2*)alloc((size_t)TOT * 8);
    unsigned short* hA = (unsigned short*)alloc((size_t)NN * HIDC * 2);
    unsigned short* hB = (unsigned short*)alloc((size_t)NN * HIDC * 2);
    float* x0      = (float*)alloc((size_t)NN * HIDC * 4);

    hipMemsetAsync(flag, 0, 4, stream);
    hipMemsetAsync(degi, 0, (size_t)NN * 4, stream);
    detect_kernel<<<256, 256, 0, stream>>>((const long long*)ei, flag);
    deg_kernel<<<(TOT + 255) / 256, 256, 0, stream>>>(ei, flag, degi);
    dinv_kernel<<<(NN + 255) / 256, 256, 0, stream>>>(degi, dinv);
    scan_part<<<SCAN_B, 256, 0, stream>>>(degi, bsum);
    scan_bsum<<<1, 256, 0, stream>>>(bsum);
    scan_final<<<SCAN_B, 256, 0, stream>>>(degi, bsum, offsets);
    hipMemcpyAsync(cursor, offsets, (size_t)NN * 4, hipMemcpyDeviceToDevice, stream);
    fill_kernel<<<(TOT + 255) / 256, 256, 0, stream>>>(ei, flag, dinv, cursor, adj);
    in_gemm<<<1024, 512, 0, stream>>>(x, w_in, b_in, hA, x0);

    unsigned short* cur = hA;
    unsigned short* nxt = hB;
    for (int l = 0; l < LLAYERS; ++l) {
        float beta = logf(0.5f / (float)(l + 1) + 1.0f);
        const float* Wl = conv_w + (size_t)l * HIDC * HIDC;
        layer_mid<<<2048, 256, 0, stream>>>(cur, nxt, x0, offsets, adj, Wl, beta);
        unsigned short* t = cur; cur = nxt; nxt = t;
    }
    out_gemm<<<1024, 256, 0, stream>>>(cur, w_out, b_out, out);
}